// Round 1
// baseline (2964.063 us; speedup 1.0000x reference)
//
#include <hip/hip_runtime.h>
#include <cstdint>
#include <cstddef>

// ---------------------------------------------------------------------------
// DockPointNet fused edge-MLP + segment-max
//   msg[e] = [x[src](32) | ppf(4) | edge_attr(11)]  (47)
//   h1 = LN(relu(msg @ W1 + b1))        (47)
//   h2 = LN(relu(h1  @ W2 + b2))        (128)
//   out[n] = max over edges with dst==n of h2 ; empty -> 0
// Strategy: wave-per-16-edges, weights in VGPRs, msg/h1 in wave-private LDS,
// LN via shfl_xor reductions, scatter-max via ordered-uint atomicMax.
// ---------------------------------------------------------------------------

#define ENC_NEGINF 0x007FFFFFu   // fenc(-inf)

__device__ __forceinline__ float wsum(float v) {
#pragma unroll
    for (int m = 1; m < 64; m <<= 1) v += __shfl_xor(v, m, 64);
    return v;
}

// monotone float -> uint mapping (order preserving, handles negatives)
__device__ __forceinline__ unsigned fenc(float f) {
    unsigned u = __float_as_uint(f);
    return (u & 0x80000000u) ? ~u : (u | 0x80000000u);
}

__global__ void init_out_kernel(unsigned* __restrict__ out, int n4) {
    int i = blockIdx.x * blockDim.x + threadIdx.x;
    if (i < n4) {
        ((uint4*)out)[i] = make_uint4(ENC_NEGINF, ENC_NEGINF, ENC_NEGINF, ENC_NEGINF);
    }
}

__global__ void finalize_out_kernel(float* __restrict__ out, int n) {
    int i = blockIdx.x * blockDim.x + threadIdx.x;
    if (i < n) {
        unsigned k = __float_as_uint(out[i]);
        float r;
        if (k == ENC_NEGINF) {
            r = 0.0f;                       // empty segment -> 0 (isfinite guard)
        } else {
            unsigned u = (k & 0x80000000u) ? (k ^ 0x80000000u) : ~k;
            r = __uint_as_float(u);
        }
        out[i] = r;
    }
}

__global__ __launch_bounds__(256) void edge_kernel(
    const float* __restrict__ x,   const float* __restrict__ pos,
    const float* __restrict__ nrm, const float* __restrict__ ea,
    const float* __restrict__ W1,  const float* __restrict__ b1,
    const float* __restrict__ g1,  const float* __restrict__ be1,
    const float* __restrict__ W2,  const float* __restrict__ b2,
    const float* __restrict__ g2,  const float* __restrict__ be2,
    const int* __restrict__ srcI,  const int* __restrict__ dstI,
    unsigned* __restrict__ out, int E, int ntiles)
{
    __shared__ float msg_s[64][48];
    __shared__ float h1_s[64][48];
    __shared__ int   dst_s[64];

    const int lane = threadIdx.x & 63;
    const int w    = threadIdx.x >> 6;   // 4 waves / block

    // ---- per-lane weight columns in registers (144 VGPRs) ----
    float w1c[48], w2a[48], w2b[48];
#pragma unroll
    for (int k = 0; k < 47; ++k) {
        w1c[k] = (lane < 47) ? W1[k * 47 + lane] : 0.0f;
        w2a[k] = W2[k * 128 + lane];
        w2b[k] = W2[k * 128 + lane + 64];
    }
    w1c[47] = 0.0f; w2a[47] = 0.0f; w2b[47] = 0.0f;

    const float b1v  = (lane < 47) ? b1[lane]  : 0.0f;
    const float g1v  = (lane < 47) ? g1[lane]  : 0.0f;
    const float be1v = (lane < 47) ? be1[lane] : 0.0f;
    const float b2v0  = b2[lane],      b2v1  = b2[lane + 64];
    const float g2v0  = g2[lane],      g2v1  = g2[lane + 64];
    const float be2v0 = be2[lane],     be2v1 = be2[lane + 64];

    for (int tile = blockIdx.x; tile < ntiles; tile += gridDim.x) {
        const int base = tile * 64 + w * 16;   // this wave's 16 edges
        const int row0 = w * 16;

        // ---------------- Phase 1: build msg rows ----------------
        // x_j copy: 2 edges per iteration (half-wave each, coalesced 128B)
#pragma unroll
        for (int i = 0; i < 8; ++i) {
            int el = i * 2 + (lane >> 5);
            int e  = base + el;
            int c  = lane & 31;
            float v = 0.0f;
            if (e < E) v = x[(size_t)srcI[e] * 32 + c];
            msg_s[row0 + el][c] = v;
        }
        // edge_attr copy: 4 edges x 11 ch per iteration (lanes 0..43)
        {
            int eg = lane / 11;
            int c  = lane - eg * 11;
            if (lane < 44) {
#pragma unroll
                for (int i = 0; i < 4; ++i) {
                    int el = i * 4 + eg;
                    int e  = base + el;
                    float v = 0.0f;
                    if (e < E) v = ea[(size_t)e * 11 + c];
                    msg_s[row0 + el][36 + c] = v;
                }
            }
        }
        // geometry: one edge per lane (lanes 0..15)
        if (lane < 16) {
            int el = lane;
            int e  = base + el;
            int s = 0, d = 0;
            if (e < E) { s = srcI[e]; d = dstI[e]; }
            float pix = pos[d * 3 + 0], piy = pos[d * 3 + 1], piz = pos[d * 3 + 2];
            float pjx = pos[s * 3 + 0], pjy = pos[s * 3 + 1], pjz = pos[s * 3 + 2];
            float nix = nrm[d * 3 + 0], niy = nrm[d * 3 + 1], niz = nrm[d * 3 + 2];
            float njx = nrm[s * 3 + 0], njy = nrm[s * 3 + 1], njz = nrm[s * 3 + 2];
            float px = pjx - pix, py = pjy - piy, pz = pjz - piz;
            float dist = sqrtf(px * px + py * py + pz * pz);
            // angle(n_i, pseudo)
            float cx = niy * pz - niz * py;
            float cy = niz * px - nix * pz;
            float cz = nix * py - niy * px;
            float a1 = atan2f(sqrtf(cx * cx + cy * cy + cz * cz),
                              nix * px + niy * py + niz * pz);
            // angle(n_j, pseudo)
            cx = njy * pz - njz * py;
            cy = njz * px - njx * pz;
            cz = njx * py - njy * px;
            float a2 = atan2f(sqrtf(cx * cx + cy * cy + cz * cz),
                              njx * px + njy * py + njz * pz);
            // angle(n_i, n_j)
            cx = niy * njz - niz * njy;
            cy = niz * njx - nix * njz;
            cz = nix * njy - niy * njx;
            float a3 = atan2f(sqrtf(cx * cx + cy * cy + cz * cz),
                              nix * njx + niy * njy + niz * njz);
            msg_s[row0 + el][32] = dist;
            msg_s[row0 + el][33] = a1;
            msg_s[row0 + el][34] = a2;
            msg_s[row0 + el][35] = a3;
            msg_s[row0 + el][47] = 0.0f;
            dst_s[row0 + el] = d;
        }
        __syncthreads();

        // ---------------- Phase 2: h1 = LN(relu(msg @ W1 + b1)) ----------------
        for (int el = 0; el < 16; ++el) {
            int e = base + el;
            if (e >= E) break;
            const float* mr = msg_s[row0 + el];
            float acc = b1v;
#pragma unroll
            for (int k = 0; k < 48; ++k) acc = fmaf(mr[k], w1c[k], acc);
            float v = fmaxf(acc, 0.0f);                     // lanes>=47 -> 0
            float mean = wsum(v) * (1.0f / 47.0f);
            float dv = (lane < 47) ? (v - mean) : 0.0f;
            float var = wsum(dv * dv) * (1.0f / 47.0f);
            float rs = rsqrtf(var + 1e-5f);
            if (lane < 48)
                h1_s[row0 + el][lane] = (lane < 47) ? (dv * rs * g1v + be1v) : 0.0f;
        }
        __syncthreads();

        // ---------------- Phase 3: h2 = LN(relu(h1 @ W2 + b2)); scatter-max ----
        for (int el = 0; el < 16; ++el) {
            int e = base + el;
            if (e >= E) break;
            const float* hr = h1_s[row0 + el];
            float a0 = b2v0, a1acc = b2v1;
#pragma unroll
            for (int k = 0; k < 48; ++k) {
                float t = hr[k];
                a0    = fmaf(t, w2a[k], a0);
                a1acc = fmaf(t, w2b[k], a1acc);
            }
            float v0 = fmaxf(a0, 0.0f);
            float v1 = fmaxf(a1acc, 0.0f);
            float mean = wsum(v0 + v1) * (1.0f / 128.0f);
            float d0 = v0 - mean, d1 = v1 - mean;
            float var = wsum(d0 * d0 + d1 * d1) * (1.0f / 128.0f);
            float rs = rsqrtf(var + 1e-5f);
            float o0 = d0 * rs * g2v0 + be2v0;
            float o1 = d1 * rs * g2v1 + be2v1;
            unsigned* orow = out + (size_t)dst_s[row0 + el] * 128;
            atomicMax(orow + lane,      fenc(o0));
            atomicMax(orow + lane + 64, fenc(o1));
        }
        __syncthreads();
    }
}

extern "C" void kernel_launch(void* const* d_in, const int* in_sizes, int n_in,
                              void* d_out, int out_size, void* d_ws, size_t ws_size,
                              hipStream_t stream) {
    const float* x   = (const float*)d_in[0];
    const float* pos = (const float*)d_in[1];
    const float* nrm = (const float*)d_in[2];
    const float* ea  = (const float*)d_in[3];
    const float* W1  = (const float*)d_in[4];
    const float* b1  = (const float*)d_in[5];
    const float* g1  = (const float*)d_in[6];
    const float* be1 = (const float*)d_in[7];
    const float* W2  = (const float*)d_in[8];
    const float* b2  = (const float*)d_in[9];
    const float* g2  = (const float*)d_in[10];
    const float* be2 = (const float*)d_in[11];
    const int*   idx = (const int*)d_in[12];

    const int N = in_sizes[0] / 32;
    const int E = in_sizes[3] / 11;
    const int* srcI = idx;
    const int* dstI = idx + E;

    unsigned* outU = (unsigned*)d_out;
    const int n = N * 128;

    init_out_kernel<<<(n / 4 + 255) / 256, 256, 0, stream>>>(outU, n / 4);

    const int ntiles = (E + 63) / 64;
    const int grid = ntiles < 4096 ? ntiles : 4096;
    edge_kernel<<<grid, 256, 0, stream>>>(x, pos, nrm, ea,
                                          W1, b1, g1, be1,
                                          W2, b2, g2, be2,
                                          srcI, dstI, outU, E, ntiles);

    finalize_out_kernel<<<(n + 255) / 256, 256, 0, stream>>>((float*)d_out, n);
}

// Round 2
// 1406.477 us; speedup vs baseline: 2.1074x; 2.1074x over previous
//
#include <hip/hip_runtime.h>
#include <cstdint>
#include <cstddef>

// ---------------------------------------------------------------------------
// DockPointNet fused edge-MLP + segment-max, f16 MFMA version.
//   msg[e](47) = [x[src] | ppf | edge_attr]
//   h1 = LN(relu(msg @ W1 + b1))   via mfma_f32_16x16x32_f16, 3 N-frags
//   h2 = LN(relu(h1  @ W2 + b2))   via mfma_f32_16x16x32_f16, 8 N-frags
//   out[n] = segment-max over dst, empty -> 0
// 64-edge tile / block, 16 edges / wave, barrier-free tile loop.
// LN uses C-fragment layout (col=lane&15, row=(lane>>4)*4+reg): 16-lane
// shfl_xor reductions give all 16 row-stats in parallel.
// ---------------------------------------------------------------------------

typedef _Float16 f16x8 __attribute__((ext_vector_type(8)));
typedef float    f32x4 __attribute__((ext_vector_type(4)));

#define ENC_NEGINF 0x007FFFFFu   // fenc(-inf)
#define LDK 72                   // padded K stride (bank-stride 4 -> 2-way, free)

__device__ __forceinline__ unsigned fenc(float f) {
    unsigned u = __float_as_uint(f);
    return (u & 0x80000000u) ? ~u : (u | 0x80000000u);
}

__global__ void init_out_kernel(unsigned* __restrict__ out, int n4) {
    int i = blockIdx.x * blockDim.x + threadIdx.x;
    if (i < n4) {
        ((uint4*)out)[i] = make_uint4(ENC_NEGINF, ENC_NEGINF, ENC_NEGINF, ENC_NEGINF);
    }
}

__global__ void finalize_out_kernel(float* __restrict__ out, int n) {
    int i = blockIdx.x * blockDim.x + threadIdx.x;
    if (i < n) {
        unsigned k = __float_as_uint(out[i]);
        float r;
        if (k == ENC_NEGINF) {
            r = 0.0f;                       // empty segment -> 0 (isfinite guard)
        } else {
            unsigned u = (k & 0x80000000u) ? (k ^ 0x80000000u) : ~k;
            r = __uint_as_float(u);
        }
        out[i] = r;
    }
}

__global__ __launch_bounds__(256) void edge_kernel(
    const float* __restrict__ x,   const float* __restrict__ pos,
    const float* __restrict__ nrm, const float* __restrict__ ea,
    const float* __restrict__ W1,  const float* __restrict__ b1,
    const float* __restrict__ g1,  const float* __restrict__ be1,
    const float* __restrict__ W2,  const float* __restrict__ b2,
    const float* __restrict__ g2,  const float* __restrict__ be2,
    const int* __restrict__ srcI,  const int* __restrict__ dstI,
    unsigned* __restrict__ out, int E, int ntiles)
{
    __shared__ _Float16 W1t[48][LDK];    // [n][k]  (B^T layout: frag = ds_read_b128)
    __shared__ _Float16 W2t[128][LDK];   // [n][k]
    __shared__ _Float16 msgA[64][LDK];   // [edge][k]
    __shared__ _Float16 h1A[64][LDK];
    __shared__ int dst_s[64];

    const int lane = threadIdx.x & 63;
    const int w    = threadIdx.x >> 6;   // 4 waves / block
    const int c16  = lane & 15;          // fragment col / A-row
    const int g    = lane >> 4;          // k-group (A/B) and row-group (C)

    // ---- stage weights to LDS, transposed + f16 + zero-padded ----
    for (int i = threadIdx.x; i < 48 * 64; i += 256) {
        int n = i >> 6, k = i & 63;
        W1t[n][k] = (n < 47 && k < 47) ? (_Float16)W1[k * 47 + n] : (_Float16)0.f;
    }
    for (int i = threadIdx.x; i < 128 * 64; i += 256) {
        int n = i >> 6, k = i & 63;
        W2t[n][k] = (k < 47) ? (_Float16)W2[k * 128 + n] : (_Float16)0.f;
    }
    // zero msg / h1 (pad cols must be non-NaN; valid cols rewritten per tile)
    for (int i = threadIdx.x; i < 64 * LDK; i += 256) {
        (&msgA[0][0])[i] = (_Float16)0.f;
        (&h1A[0][0])[i]  = (_Float16)0.f;
    }

    // ---- per-lane LN params ----
    float b1v[3], g1v[3], be1v[3];
#pragma unroll
    for (int n = 0; n < 3; ++n) {
        int cc = n * 16 + c16;
        bool vld = cc < 47;
        b1v[n]  = vld ? b1[cc]  : 0.f;
        g1v[n]  = vld ? g1[cc]  : 0.f;
        be1v[n] = vld ? be1[cc] : 0.f;
    }
    float b2v[8], g2v[8], be2v[8];
#pragma unroll
    for (int n = 0; n < 8; ++n) {
        int cc = n * 16 + c16;
        b2v[n] = b2[cc]; g2v[n] = g2[cc]; be2v[n] = be2[cc];
    }
    __syncthreads();

    for (int tile = blockIdx.x; tile < ntiles; tile += gridDim.x) {
        const int base = tile * 64 + w * 16;   // this wave's 16 edges
        const int row0 = w * 16;

        // ---------------- Phase 1: build msg rows (wave-private) ----------------
        // x_j: 2 edges / iter, half-wave each (coalesced 128B)
#pragma unroll
        for (int i = 0; i < 8; ++i) {
            int el = i * 2 + (lane >> 5);
            int e  = base + el;
            int c  = lane & 31;
            float v = 0.f;
            if (e < E) v = x[(size_t)srcI[e] * 32 + c];
            msgA[row0 + el][c] = (_Float16)v;
        }
        // edge_attr: lanes 0..43 cover 4 edges x 11 ch per iter
        if (lane < 44) {
            int eg = lane / 11, c = lane - eg * 11;
#pragma unroll
            for (int i = 0; i < 4; ++i) {
                int el = i * 4 + eg;
                int e  = base + el;
                float v = 0.f;
                if (e < E) v = ea[(size_t)e * 11 + c];
                msgA[row0 + el][36 + c] = (_Float16)v;
            }
        }
        // geometry: lane = g*16 + el, g = which angle (0..2), el = edge 0..15
        if (lane < 48) {
            int el = c16;
            int e  = base + el;
            int s = 0, d = 0;
            bool vld = e < E;
            if (vld) { s = srcI[e]; d = dstI[e]; }
            float pix = pos[d * 3 + 0], piy = pos[d * 3 + 1], piz = pos[d * 3 + 2];
            float pjx = pos[s * 3 + 0], pjy = pos[s * 3 + 1], pjz = pos[s * 3 + 2];
            float nix = nrm[d * 3 + 0], niy = nrm[d * 3 + 1], niz = nrm[d * 3 + 2];
            float njx = nrm[s * 3 + 0], njy = nrm[s * 3 + 1], njz = nrm[s * 3 + 2];
            float px = pjx - pix, py = pjy - piy, pz = pjz - piz;
            float v1x, v1y, v1z, v2x, v2y, v2z;
            if (g == 0)      { v1x = nix; v1y = niy; v1z = niz; v2x = px;  v2y = py;  v2z = pz;  }
            else if (g == 1) { v1x = njx; v1y = njy; v1z = njz; v2x = px;  v2y = py;  v2z = pz;  }
            else             { v1x = nix; v1y = niy; v1z = niz; v2x = njx; v2y = njy; v2z = njz; }
            float cx = v1y * v2z - v1z * v2y;
            float cy = v1z * v2x - v1x * v2z;
            float cz = v1x * v2y - v1y * v2x;
            float ang = atan2f(sqrtf(cx * cx + cy * cy + cz * cz),
                               v1x * v2x + v1y * v2y + v1z * v2z);
            msgA[row0 + el][33 + g] = (_Float16)ang;
            if (g == 0) {
                msgA[row0 + el][32] = (_Float16)sqrtf(px * px + py * py + pz * pz);
                dst_s[row0 + el] = vld ? d : -1;
            }
        }
        // no barrier needed: all LDS rows above are wave-private

        // ---------------- Phase 2: GEMM1 (16x48 = 6 MFMA) + LN1 ----------------
        f32x4 acc1[3];
#pragma unroll
        for (int n = 0; n < 3; ++n) acc1[n] = (f32x4){0.f, 0.f, 0.f, 0.f};
#pragma unroll
        for (int ks = 0; ks < 2; ++ks) {
            f16x8 a = *(const f16x8*)&msgA[row0 + c16][ks * 32 + g * 8];
#pragma unroll
            for (int n = 0; n < 3; ++n) {
                f16x8 b = *(const f16x8*)&W1t[n * 16 + c16][ks * 32 + g * 8];
                acc1[n] = __builtin_amdgcn_mfma_f32_16x16x32_f16(a, b, acc1[n], 0, 0, 0);
            }
        }
#pragma unroll
        for (int q = 0; q < 4; ++q) {
            float t0 = fmaxf(acc1[0][q] + b1v[0], 0.f);
            float t1 = fmaxf(acc1[1][q] + b1v[1], 0.f);
            float t2 = fmaxf(acc1[2][q] + b1v[2], 0.f);   // col 47 -> 0 (W1t row 47 zero, b1v 0)
            float s = t0 + t1 + t2;
            float s2 = t0 * t0 + t1 * t1 + t2 * t2;
#pragma unroll
            for (int m = 1; m < 16; m <<= 1) {
                s  += __shfl_xor(s,  m, 64);
                s2 += __shfl_xor(s2, m, 64);
            }
            float mu  = s * (1.f / 47.f);
            float var = s2 * (1.f / 47.f) - mu * mu;
            float rs  = rsqrtf(var + 1e-5f);
            int r = row0 + 4 * g + q;
            h1A[r][c16]      = (_Float16)((t0 - mu) * rs * g1v[0] + be1v[0]);
            h1A[r][16 + c16] = (_Float16)((t1 - mu) * rs * g1v[1] + be1v[1]);
            h1A[r][32 + c16] = (_Float16)((t2 - mu) * rs * g1v[2] + be1v[2]);  // col47 -> 0
        }

        // ---------------- Phase 3: GEMM2 (16x128 = 16 MFMA) + LN2 + scatter ----
        f32x4 acc2[8];
#pragma unroll
        for (int n = 0; n < 8; ++n) acc2[n] = (f32x4){0.f, 0.f, 0.f, 0.f};
#pragma unroll
        for (int ks = 0; ks < 2; ++ks) {
            f16x8 a = *(const f16x8*)&h1A[row0 + c16][ks * 32 + g * 8];
#pragma unroll
            for (int n = 0; n < 8; ++n) {
                f16x8 b = *(const f16x8*)&W2t[n * 16 + c16][ks * 32 + g * 8];
                acc2[n] = __builtin_amdgcn_mfma_f32_16x16x32_f16(a, b, acc2[n], 0, 0, 0);
            }
        }
        int4 dd = *(const int4*)&dst_s[row0 + 4 * g];
#pragma unroll
        for (int q = 0; q < 4; ++q) {
            float t[8];
            float s = 0.f, s2 = 0.f;
#pragma unroll
            for (int n = 0; n < 8; ++n) {
                t[n] = fmaxf(acc2[n][q] + b2v[n], 0.f);
                s += t[n]; s2 += t[n] * t[n];
            }
#pragma unroll
            for (int m = 1; m < 16; m <<= 1) {
                s  += __shfl_xor(s,  m, 64);
                s2 += __shfl_xor(s2, m, 64);
            }
            float mu  = s * (1.f / 128.f);
            float var = s2 * (1.f / 128.f) - mu * mu;
            float rs  = rsqrtf(var + 1e-5f);
            int d = (&dd.x)[q];
            if (d >= 0) {
                unsigned* orow = out + (size_t)d * 128u;
#pragma unroll
                for (int n = 0; n < 8; ++n) {
                    float o = (t[n] - mu) * rs * g2v[n] + be2v[n];
                    atomicMax(orow + n * 16 + c16, fenc(o));
                }
            }
        }
    }
}

extern "C" void kernel_launch(void* const* d_in, const int* in_sizes, int n_in,
                              void* d_out, int out_size, void* d_ws, size_t ws_size,
                              hipStream_t stream) {
    const float* x   = (const float*)d_in[0];
    const float* pos = (const float*)d_in[1];
    const float* nrm = (const float*)d_in[2];
    const float* ea  = (const float*)d_in[3];
    const float* W1  = (const float*)d_in[4];
    const float* b1  = (const float*)d_in[5];
    const float* g1  = (const float*)d_in[6];
    const float* be1 = (const float*)d_in[7];
    const float* W2  = (const float*)d_in[8];
    const float* b2  = (const float*)d_in[9];
    const float* g2  = (const float*)d_in[10];
    const float* be2 = (const float*)d_in[11];
    const int*   idx = (const int*)d_in[12];

    const int N = in_sizes[0] / 32;
    const int E = in_sizes[3] / 11;
    const int* srcI = idx;
    const int* dstI = idx + E;

    unsigned* outU = (unsigned*)d_out;
    const int n = N * 128;

    init_out_kernel<<<(n / 4 + 255) / 256, 256, 0, stream>>>(outU, n / 4);

    const int ntiles = (E + 63) / 64;
    const int grid = ntiles < 4096 ? ntiles : 4096;
    edge_kernel<<<grid, 256, 0, stream>>>(x, pos, nrm, ea,
                                          W1, b1, g1, be1,
                                          W2, b2, g2, be2,
                                          srcI, dstI, outU, E, ntiles);

    finalize_out_kernel<<<(n + 255) / 256, 256, 0, stream>>>((float*)d_out, n);
}